// Round 13
// baseline (454.874 us; speedup 1.0000x reference)
//
#include <hip/hip_runtime.h>
#include <hip/hip_cooperative_groups.h>

namespace cg = cooperative_groups;

#define NN 65536
#define NE 262144
#define NG 2048
#define NTHR 256

typedef __attribute__((ext_vector_type(16))) float f32x16;
typedef __attribute__((ext_vector_type(4)))  float f32x4;
typedef __attribute__((ext_vector_type(8)))  __bf16 bf16x8;

__device__ inline unsigned pack2(float a, float b) {
    return __builtin_amdgcn_perm(__float_as_uint(b), __float_as_uint(a), 0x07060302u);
}
__device__ inline float lof(float p) {
    return p - __uint_as_float(__float_as_uint(p) & 0xffff0000u);
}
__device__ inline bf16x8 asb(uint4 u) { return __builtin_bit_cast(bf16x8, u); }
__device__ inline void wave_lds_fence() {
    asm volatile("s_waitcnt lgkmcnt(0)" ::: "memory");
}

struct Params {
    const float *x, *ea;
    const int *ei, *batch;
    const float *w1a, *b1a, *w2a, *b2a, *roota, *biasa;
    const float *w1b, *b1b, *w2b, *b2b, *rootb, *biasb;
    const float *gw1, *gb1, *gw2, *gb2;
    const float *l1w, *l1b, *l2w, *l2b;
    float *out;
    float *h1, *h2, *x_att;
    int *goffs, *offs, *cnt, *cur, *bsum, *boff;
    int2 *epair;
    unsigned *f1, *f2;
    float *msg;
};

// ===================== single cooperative mega-kernel ========================
__global__ __launch_bounds__(256, 2) void k_all(Params P)
{
    cg::grid_group grid = cg::this_grid();
    __shared__ __align__(16) char smem[34816];
    const int tid   = threadIdx.x;
    const int bid   = blockIdx.x;
    const int gsz   = gridDim.x * NTHR;
    const int nwave = gridDim.x * 4;
    const int gtid  = bid*NTHR + tid;
    const int lane  = tid & 63;
    const int wid   = tid >> 6;
    const int gwave = bid*4 + wid;

    // ---- P0: setup (zero cnt/cur, goffs, W-frag prep) ----
    for (int t = gtid; t < 131072; t += gsz) {
        if (t < NN) { P.cnt[t] = 0; P.cur[t] = 0; }
        if (t <= NG) {
            int lo = 0, hi = NN;
            while (lo < hi) {
                int mid = (lo + hi) >> 1;
                if (P.batch[mid] < t) lo = mid + 1; else hi = mid;
            }
            P.goffs[t] = lo;
        }
        if (t < 17408) {
            int c = t / 8704;
            int r = t - c * 8704;
            int d = r & 3;
            int l = (r >> 2) & 63;
            int tt = (r >> 8) & 1;
            int s = r >> 9;
            if (c == 0) {
                int n = l & 31, g = l >> 5;
                int j0 = 2*d;
                int c0 = (g*8 + j0)*32 + n;
                int c1 = c0 + 32;
                float a = (s < 16) ? P.w2a[s*512 + c0] : P.b2a[c0];
                float b = (s < 16) ? P.w2a[s*512 + c1] : P.b2a[c1];
                P.f1[r] = tt ? pack2(lof(a), lof(b)) : pack2(a, b);
            } else {
                int n = l & 15, g = l >> 4;
                int j0 = 2*d;
                int c0 = (g*8 + j0)*16 + n;
                int c1 = c0 + 16;
                float a = (s < 16) ? P.w2b[s*512 + c0] : P.b2b[c0];
                float b = (s < 16) ? P.w2b[s*512 + c1] : P.b2b[c1];
                P.f2[r] = tt ? pack2(lof(a), lof(b)) : pack2(a, b);
            }
        }
    }
    grid.sync();

    // ---- P1: hist + fused gate/attention pool ----
    {
        for (int e = gtid; e < NE; e += gsz)
            atomicAdd(&P.cnt[P.ei[NE + e]], 1);

        float* sgb = (float*)smem;                    // 4 waves x 1024 floats
        float* sw  = (float*)(smem + 16384);          // 256
        float* sb  = sw + 256;                        // 16
        float* sw2 = sb + 16;                         // 16
        float* sb2 = sw2 + 16;                        // 1
        if (tid < 256) sw[tid] = P.gw1[tid];
        if (tid < 16) { sb[tid] = P.gb1[tid]; sw2[tid] = P.gw2[tid]; }
        if (tid == 0) sb2[0] = P.gb2[0];
        __syncthreads();

        float* gb = sgb + wid*1024;
        for (int g = gwave; g < NG; g += nwave) {
            const int s = P.goffs[g], e = P.goffs[g + 1];
            const int cntg = e - s;
            if (cntg <= 0) {
                if (lane < 16) P.x_att[g*16 + lane] = 0.f;
                continue;
            }
            const int cap = cntg < 1024 ? cntg : 1024;
            for (int ii = lane; ii < cap; ii += 64) {
                const float4* xp = (const float4*)(P.x + (size_t)(s + ii) * 16);
                float xv[16];
#pragma unroll
                for (int i = 0; i < 4; ++i) {
                    float4 t4 = xp[i];
                    xv[4*i] = t4.x; xv[4*i+1] = t4.y; xv[4*i+2] = t4.z; xv[4*i+3] = t4.w;
                }
                float gv = sb2[0];
#pragma unroll
                for (int j = 0; j < 16; ++j) {
                    float a = sb[j];
#pragma unroll
                    for (int i = 0; i < 16; ++i) a += xv[i] * sw[i*16 + j];
                    gv += fmaxf(a, 0.f) * sw2[j];
                }
                gb[ii] = gv;
            }
            wave_lds_fence();
            float m = -1e30f;
            for (int ii = lane; ii < cap; ii += 64) m = fmaxf(m, gb[ii]);
#pragma unroll
            for (int d = 32; d; d >>= 1) m = fmaxf(m, __shfl_xor(m, d));
            float sum = 0.f;
            for (int ii = lane; ii < cap; ii += 64) {
                float ev = expf(gb[ii] - m);
                gb[ii] = ev;
                sum += ev;
            }
#pragma unroll
            for (int d = 32; d; d >>= 1) sum += __shfl_xor(sum, d);
            const float inv = 1.f / sum;
            wave_lds_fence();
            const int f = lane & 15, sub = lane >> 4;
            float acc = 0.f;
            for (int ii = sub; ii < cap; ii += 4)
                acc += gb[ii] * inv * P.x[(size_t)(s + ii)*16 + f];
            acc += __shfl_xor(acc, 16);
            acc += __shfl_xor(acc, 32);
            if (lane < 16) P.x_att[g*16 + f] = acc;
            wave_lds_fence();
        }
    }
    grid.sync();

    // ---- P2: scan within 256-chunks ----
    {
        int* s = (int*)smem;
        for (int c = bid; c < 256; c += gridDim.x) {
            int v = P.cnt[c*256 + tid];
            __syncthreads();
            s[tid] = v;
            __syncthreads();
#pragma unroll
            for (int d = 1; d < 256; d <<= 1) {
                int add = (tid >= d) ? s[tid - d] : 0;
                __syncthreads();
                s[tid] += add;
                __syncthreads();
            }
            P.offs[c*256 + tid] = s[tid] - v;
            if (tid == 255) P.bsum[c] = s[255];
        }
    }
    grid.sync();

    // ---- P3: top-level scan (block 0) ----
    if (bid == 0) {
        int* s = (int*)smem;
        int v = P.bsum[tid];
        __syncthreads();
        s[tid] = v;
        __syncthreads();
#pragma unroll
        for (int d = 1; d < 256; d <<= 1) {
            int add = (tid >= d) ? s[tid - d] : 0;
            __syncthreads();
            s[tid] += add;
            __syncthreads();
        }
        P.boff[tid] = s[tid] - v;
    }
    grid.sync();

    // ---- P4: add block offsets ----
    for (int i = gtid; i < NN; i += gsz) P.offs[i] += P.boff[i >> 8];
    if (gtid == 0) P.offs[NN] = NE;
    grid.sync();

    // ---- P5: scatter ----
    for (int e = gtid; e < NE; e += gsz) {
        int d = P.ei[NE + e];
        int pos = P.offs[d] + atomicAdd(&P.cur[d], 1);
        P.epair[pos] = make_int2(e, P.ei[e]);
    }
    grid.sync();

    // ---- P6: conv1 (MFMA 32x32x16, dual acc, table in LDS) ----
    {
        uint4* tab = (uint4*)smem;
        __syncthreads();
        for (int i = tid; i < 2176; i += 256) tab[i] = ((const uint4*)P.f1)[i];
        __syncthreads();
        const int m = lane & 31, g8 = lane >> 5;
        for (int tile = gwave; tile < NE/32; tile += nwave) {
            const int p = tile*32 + m;
            const int2 ep = P.epair[p];
            const int e = ep.x, src = ep.y;
            float xs[8];
            {
                const float4* xp = (const float4*)(P.x + (size_t)src*16 + g8*8);
                float4 aa = xp[0], bb = xp[1];
                xs[0]=aa.x; xs[1]=aa.y; xs[2]=aa.z; xs[3]=aa.w;
                xs[4]=bb.x; xs[5]=bb.y; xs[6]=bb.z; xs[7]=bb.w;
            }
            float h[17];
            {
                const float2 e01 = *(const float2*)(P.ea + (size_t)e*6);
                const float2 e23 = *(const float2*)(P.ea + (size_t)e*6 + 2);
                const float2 e45 = *(const float2*)(P.ea + (size_t)e*6 + 4);
                const float a0=e01.x, a1=e01.y, a2=e23.x, a3=e23.y, a4=e45.x, a5=e45.y;
#pragma unroll
                for (int j = 0; j < 16; ++j) {
                    float c = P.b1a[j];
                    c += a0*P.w1a[0*16+j]; c += a1*P.w1a[1*16+j]; c += a2*P.w1a[2*16+j];
                    c += a3*P.w1a[3*16+j]; c += a4*P.w1a[4*16+j]; c += a5*P.w1a[5*16+j];
                    h[j] = fmaxf(c, 0.f);
                }
                h[16] = 1.f;
            }
            f32x16 acc0 = {}, acc1 = {};
#pragma unroll
            for (int s = 0; s < 17; ++s) {
                const float hs = h[s];
                float p0 = hs*xs[0], p1 = hs*xs[1], p2 = hs*xs[2], p3 = hs*xs[3];
                float p4 = hs*xs[4], p5 = hs*xs[5], p6 = hs*xs[6], p7 = hs*xs[7];
                uint4 uh = { pack2(p0,p1), pack2(p2,p3), pack2(p4,p5), pack2(p6,p7) };
                uint4 ul = { pack2(lof(p0),lof(p1)), pack2(lof(p2),lof(p3)),
                             pack2(lof(p4),lof(p5)), pack2(lof(p6),lof(p7)) };
                uint4 wh = tab[(s*2+0)*64 + lane];
                uint4 wl = tab[(s*2+1)*64 + lane];
                if (s & 1) {
                    acc1 = __builtin_amdgcn_mfma_f32_32x32x16_bf16(asb(uh), asb(wh), acc1, 0, 0, 0);
                    acc1 = __builtin_amdgcn_mfma_f32_32x32x16_bf16(asb(uh), asb(wl), acc1, 0, 0, 0);
                    acc1 = __builtin_amdgcn_mfma_f32_32x32x16_bf16(asb(ul), asb(wh), acc1, 0, 0, 0);
                } else {
                    acc0 = __builtin_amdgcn_mfma_f32_32x32x16_bf16(asb(uh), asb(wh), acc0, 0, 0, 0);
                    acc0 = __builtin_amdgcn_mfma_f32_32x32x16_bf16(asb(uh), asb(wl), acc0, 0, 0, 0);
                    acc0 = __builtin_amdgcn_mfma_f32_32x32x16_bf16(asb(ul), asb(wh), acc0, 0, 0, 0);
                }
            }
            float* mbase = P.msg + (size_t)tile*32*32;
            const int rb = g8*4;
#pragma unroll
            for (int r = 0; r < 16; ++r) {
                int mr = (r&3) + 8*(r>>2) + rb;
                mbase[(size_t)mr*32 + m] = acc0[r] + acc1[r];
            }
        }
    }
    grid.sync();

    // ---- P7: reduce1 ----
    {
        float* s_r = (float*)smem;     // 512
        float* s_b = s_r + 512;        // 32
        __syncthreads();
        for (int i = tid; i < 512; i += 256) s_r[i] = P.roota[i];
        if (tid < 32) s_b[tid] = P.biasa[tid];
        __syncthreads();
        const float4* s_r4 = (const float4*)s_r;
        for (int gid = gtid; gid < NN*8; gid += gsz) {
            int n = gid >> 3, q = gid & 7;
            int s = P.offs[n], e = P.offs[n + 1];
            float4 acc = make_float4(s_b[4*q], s_b[4*q+1], s_b[4*q+2], s_b[4*q+3]);
            const float* xp = P.x + (size_t)n * 16;
#pragma unroll
            for (int i = 0; i < 16; ++i) {
                float xi = xp[i];
                float4 w = s_r4[i*8 + q];
                acc.x += xi*w.x; acc.y += xi*w.y; acc.z += xi*w.z; acc.w += xi*w.w;
            }
            for (int p = s; p < e; ++p) {
                float4 mr = ((const float4*)(P.msg + (size_t)p * 32))[q];
                acc.x += mr.x; acc.y += mr.y; acc.z += mr.z; acc.w += mr.w;
            }
            acc.x = fmaxf(acc.x, 0.f); acc.y = fmaxf(acc.y, 0.f);
            acc.z = fmaxf(acc.z, 0.f); acc.w = fmaxf(acc.w, 0.f);
            ((float4*)(P.h1 + (size_t)n * 32))[q] = acc;
        }
    }
    grid.sync();

    // ---- P8: conv2 (h-hoisted MFMA 16x16x32; shfl output transpose) ----
    {
        uint4* tab = (uint4*)smem;
        __syncthreads();
        for (int i = tid; i < 2176; i += 256) tab[i] = ((const uint4*)P.f2)[i];
        __syncthreads();
        const int m = lane & 15, g8 = lane >> 4;
        const int srcl = (lane & 3) * 16 + (lane >> 2);   // shfl source lane
        for (int tile = gwave; tile < NE/16; tile += nwave) {
            const int p = tile*16 + m;
            const int2 ep = P.epair[p];
            const int e = ep.x, src = ep.y;
            uint4 xh, xl;
            {
                const float4* xp = (const float4*)(P.h1 + (size_t)src*32 + g8*8);
                float4 aa = xp[0], bb = xp[1];
                xh = (uint4){ pack2(aa.x,aa.y), pack2(aa.z,aa.w), pack2(bb.x,bb.y), pack2(bb.z,bb.w) };
                xl = (uint4){ pack2(lof(aa.x),lof(aa.y)), pack2(lof(aa.z),lof(aa.w)),
                              pack2(lof(bb.x),lof(bb.y)), pack2(lof(bb.z),lof(bb.w)) };
            }
            float h[17];
            {
                const float2 e01 = *(const float2*)(P.ea + (size_t)e*6);
                const float2 e23 = *(const float2*)(P.ea + (size_t)e*6 + 2);
                const float2 e45 = *(const float2*)(P.ea + (size_t)e*6 + 4);
                const float a0=e01.x, a1=e01.y, a2=e23.x, a3=e23.y, a4=e45.x, a5=e45.y;
#pragma unroll
                for (int j = 0; j < 16; ++j) {
                    float c = P.b1b[j];
                    c += a0*P.w1b[0*16+j]; c += a1*P.w1b[1*16+j]; c += a2*P.w1b[2*16+j];
                    c += a3*P.w1b[3*16+j]; c += a4*P.w1b[4*16+j]; c += a5*P.w1b[5*16+j];
                    h[j] = fmaxf(c, 0.f);
                }
                h[16] = 1.f;
            }
            f32x4 macc = {};
#pragma unroll
            for (int s = 0; s < 17; ++s) {
                uint4 wh = tab[(s*2+0)*64 + lane];
                uint4 wl = tab[(s*2+1)*64 + lane];
                f32x4 t = {};
                t = __builtin_amdgcn_mfma_f32_16x16x32_bf16(asb(wh), asb(xh), t, 0, 0, 0);
                t = __builtin_amdgcn_mfma_f32_16x16x32_bf16(asb(wl), asb(xh), t, 0, 0, 0);
                t = __builtin_amdgcn_mfma_f32_16x16x32_bf16(asb(wh), asb(xl), t, 0, 0, 0);
                const float hs = h[s];
                macc.x += hs*t.x; macc.y += hs*t.y; macc.z += hs*t.z; macc.w += hs*t.w;
            }
            // D element (o = g8*4+r, e = m) lives in lane (o>>2)*16+e, reg r.
            // Lane l stores msg row e'=l>>2, floats o in [4*(l&3), 4*(l&3)+4).
            float o0 = __shfl(macc.x, srcl);
            float o1 = __shfl(macc.y, srcl);
            float o2 = __shfl(macc.z, srcl);
            float o3 = __shfl(macc.w, srcl);
            float4* mb = (float4*)(P.msg + (size_t)tile*256);
            mb[lane] = make_float4(o0, o1, o2, o3);
        }
    }
    grid.sync();

    // ---- P9: reduce2 ----
    {
        float* s_r = (float*)smem;     // 512
        float* s_b = s_r + 512;        // 16
        __syncthreads();
        for (int i = tid; i < 512; i += 256) s_r[i] = P.rootb[i];
        if (tid < 16) s_b[tid] = P.biasb[tid];
        __syncthreads();
        const float4* s_r4 = (const float4*)s_r;
        for (int gid = gtid; gid < NN*4; gid += gsz) {
            int n = gid >> 2, q = gid & 3;
            int s = P.offs[n], e = P.offs[n + 1];
            float4 acc = make_float4(s_b[4*q], s_b[4*q+1], s_b[4*q+2], s_b[4*q+3]);
            const float* xp = P.h1 + (size_t)n * 32;
#pragma unroll
            for (int i = 0; i < 32; ++i) {
                float xi = xp[i];
                float4 w = s_r4[i*4 + q];
                acc.x += xi*w.x; acc.y += xi*w.y; acc.z += xi*w.z; acc.w += xi*w.w;
            }
            for (int p = s; p < e; ++p) {
                float4 mr = ((const float4*)(P.msg + (size_t)p * 16))[q];
                acc.x += mr.x; acc.y += mr.y; acc.z += mr.z; acc.w += mr.w;
            }
            acc.x = fmaxf(acc.x, 0.f); acc.y = fmaxf(acc.y, 0.f);
            acc.z = fmaxf(acc.z, 0.f); acc.w = fmaxf(acc.w, 0.f);
            ((float4*)(P.h2 + (size_t)n * 16))[q] = acc;
        }
    }
    grid.sync();

    // ---- P10: mean pool + concat + head ----
    {
        float* v = (float*)smem + wid*64;      // 32 v + 8 hmid per wave
        float* hmid = v + 32;
        __syncthreads();
        for (int g = gwave; g < NG; g += nwave) {
            const int s = P.goffs[g], e = P.goffs[g + 1];
            const int f = lane & 15, sub = lane >> 4;
            float acc = 0.f;
            for (int i = s + sub; i < e; i += 4) acc += P.h2[(size_t)i*16 + f];
            acc += __shfl_xor(acc, 16);
            acc += __shfl_xor(acc, 32);
            float cntg = fmaxf((float)(e - s), 1.0f);
            if (lane < 16) {
                v[lane]      = acc / cntg;
                v[16 + lane] = P.x_att[g*16 + lane];
            }
            wave_lds_fence();
            if (lane < 8) {
                float a = P.l1b[lane];
#pragma unroll
                for (int i = 0; i < 32; ++i) a += v[i] * P.l1w[i*8 + lane];
                hmid[lane] = a;
            }
            wave_lds_fence();
            if (lane == 0) {
                float a = P.l2b[0];
#pragma unroll
                for (int j = 0; j < 8; ++j) a += hmid[j] * P.l2w[j];
                P.out[g] = a;
            }
            wave_lds_fence();
        }
    }
}

// ===================== fallback multi-kernel path (R10, known-good) ==========
__global__ __launch_bounds__(256) void k_setup(
    const int* __restrict__ batch,
    const float* __restrict__ w2a, const float* __restrict__ b2a,
    const float* __restrict__ w2b, const float* __restrict__ b2c,
    int* __restrict__ cnt, int* __restrict__ cur, int* __restrict__ goffs,
    unsigned* __restrict__ f1, unsigned* __restrict__ f2)
{
    int t = blockIdx.x * 256 + threadIdx.x;
    if (t < NN) { cnt[t] = 0; cur[t] = 0; }
    if (t <= NG) {
        int lo = 0, hi = NN;
        while (lo < hi) {
            int mid = (lo + hi) >> 1;
            if (batch[mid] < t) lo = mid + 1; else hi = mid;
        }
        goffs[t] = lo;
    }
    if (t < 17408) {
        int c = t / 8704;
        int r = t - c * 8704;
        int d = r & 3;
        int l = (r >> 2) & 63;
        int tt = (r >> 8) & 1;
        int s = r >> 9;
        if (c == 0) {
            int n = l & 31, g = l >> 5;
            int j0 = 2*d;
            int c0 = (g*8 + j0)*32 + n;
            int c1 = c0 + 32;
            float a = (s < 16) ? w2a[s*512 + c0] : b2a[c0];
            float b = (s < 16) ? w2a[s*512 + c1] : b2a[c1];
            f1[r] = tt ? pack2(lof(a), lof(b)) : pack2(a, b);
        } else {
            int n = l & 15, g = l >> 4;
            int j0 = 2*d;
            int c0 = (g*8 + j0)*16 + n;
            int c1 = c0 + 16;
            float a = (s < 16) ? w2b[s*512 + c0] : b2c[c0];
            float b = (s < 16) ? w2b[s*512 + c1] : b2c[c1];
            f2[r] = tt ? pack2(lof(a), lof(b)) : pack2(a, b);
        }
    }
}

__global__ __launch_bounds__(64) void k_gateatt(const float* __restrict__ x,
    const float* __restrict__ gw1, const float* __restrict__ gb1,
    const float* __restrict__ gw2, const float* __restrict__ gb2,
    const int* __restrict__ goffs, float* __restrict__ x_att)
{
    __shared__ float sw[256];
    __shared__ float sb[16];
    __shared__ float sw2[16];
    __shared__ float sb2;
    __shared__ float gb[1024];
    const int g = blockIdx.x;
    const int lane = threadIdx.x;
    for (int i = lane; i < 256; i += 64) sw[i] = gw1[i];
    if (lane < 16) { sb[lane] = gb1[lane]; sw2[lane] = gw2[lane]; }
    if (lane == 0) sb2 = gb2[0];
    const int s = goffs[g], e = goffs[g + 1];
    const int cnt = e - s;
    if (cnt <= 0) {
        if (lane < 16) x_att[g*16 + lane] = 0.f;
        return;
    }
    const int cap = cnt < 1024 ? cnt : 1024;
    __syncthreads();
    for (int ii = lane; ii < cap; ii += 64) {
        const float4* xp = (const float4*)(x + (size_t)(s + ii) * 16);
        float xv[16];
#pragma unroll
        for (int i = 0; i < 4; ++i) {
            float4 tt = xp[i];
            xv[4*i] = tt.x; xv[4*i+1] = tt.y; xv[4*i+2] = tt.z; xv[4*i+3] = tt.w;
        }
        float gv = sb2;
#pragma unroll
        for (int j = 0; j < 16; ++j) {
            float a = sb[j];
#pragma unroll
            for (int i = 0; i < 16; ++i) a += xv[i] * sw[i*16 + j];
            gv += fmaxf(a, 0.f) * sw2[j];
        }
        gb[ii] = gv;
    }
    __syncthreads();
    float m = -1e30f;
    for (int ii = lane; ii < cap; ii += 64) m = fmaxf(m, gb[ii]);
#pragma unroll
    for (int d = 32; d; d >>= 1) m = fmaxf(m, __shfl_xor(m, d));
    float sum = 0.f;
    for (int ii = lane; ii < cap; ii += 64) {
        float ev = expf(gb[ii] - m);
        gb[ii] = ev;
        sum += ev;
    }
#pragma unroll
    for (int d = 32; d; d >>= 1) sum += __shfl_xor(sum, d);
    const float inv = 1.f / sum;
    __syncthreads();
    const int f = lane & 15, sub = lane >> 4;
    float acc = 0.f;
    for (int ii = sub; ii < cap; ii += 4)
        acc += gb[ii] * inv * x[(size_t)(s + ii)*16 + f];
    acc += __shfl_xor(acc, 16);
    acc += __shfl_xor(acc, 32);
    if (lane < 16) x_att[g*16 + f] = acc;
}

__global__ __launch_bounds__(256) void k_hist(const int* __restrict__ ei, int* __restrict__ cnt)
{
    int e = blockIdx.x * 256 + threadIdx.x;
    if (e >= NE) return;
    atomicAdd(&cnt[ei[NE + e]], 1);
}

__global__ __launch_bounds__(256) void k_scan_blk(const int* __restrict__ cnt,
    int* __restrict__ offs, int* __restrict__ bsum)
{
    __shared__ int s[256];
    int t = threadIdx.x, b = blockIdx.x;
    int v = cnt[b*256 + t];
    s[t] = v;
    __syncthreads();
#pragma unroll
    for (int d = 1; d < 256; d <<= 1) {
        int add = (t >= d) ? s[t - d] : 0;
        __syncthreads();
        s[t] += add;
        __syncthreads();
    }
    offs[b*256 + t] = s[t] - v;
    if (t == 255) bsum[b] = s[255];
}

__global__ __launch_bounds__(256) void k_scan_top(const int* __restrict__ bsum,
    int* __restrict__ boff)
{
    __shared__ int s[256];
    int t = threadIdx.x;
    int v = bsum[t];
    s[t] = v;
    __syncthreads();
#pragma unroll
    for (int d = 1; d < 256; d <<= 1) {
        int add = (t >= d) ? s[t - d] : 0;
        __syncthreads();
        s[t] += add;
        __syncthreads();
    }
    boff[t] = s[t] - v;
}

__global__ __launch_bounds__(256) void k_scan_add(int* __restrict__ offs,
    const int* __restrict__ boff)
{
    int i = blockIdx.x * 256 + threadIdx.x;
    if (i == 0) offs[NN] = NE;
    if (i >= NN) return;
    offs[i] += boff[i >> 8];
}

__global__ __launch_bounds__(256) void k_scatter(const int* __restrict__ ei,
    const int* __restrict__ offs, int* __restrict__ cur, int2* __restrict__ epair)
{
    int e = blockIdx.x * 256 + threadIdx.x;
    if (e >= NE) return;
    int d = ei[NE + e];
    int pos = offs[d] + atomicAdd(&cur[d], 1);
    epair[pos] = make_int2(e, ei[e]);
}

__global__ __launch_bounds__(256) void k_conv1(
    const float* __restrict__ x, const float* __restrict__ ea,
    const int2* __restrict__ epair,
    const float* __restrict__ w1, const float* __restrict__ b1,
    const unsigned* __restrict__ bfrag, float* __restrict__ msg)
{
    __shared__ uint4 s_tab[17*2*64];
    const int tid  = threadIdx.x;
    for (int i = tid; i < 17*2*64; i += 256) s_tab[i] = ((const uint4*)bfrag)[i];
    __syncthreads();
    const int lane = tid & 63;
    const int wid  = tid >> 6;
    const int m    = lane & 31;
    const int g    = lane >> 5;

    const int tile = blockIdx.x*4 + wid;
    const int p    = tile*32 + m;
    const int2 ep  = epair[p];
    const int e    = ep.x, src = ep.y;

    float xs[8];
    {
        const float4* xp = (const float4*)(x + (size_t)src*16 + g*8);
        float4 aa = xp[0], bb = xp[1];
        xs[0]=aa.x; xs[1]=aa.y; xs[2]=aa.z; xs[3]=aa.w;
        xs[4]=bb.x; xs[5]=bb.y; xs[6]=bb.z; xs[7]=bb.w;
    }
    float h[17];
    {
        const float2 e01 = *(const float2*)(ea + (size_t)e*6);
        const float2 e23 = *(const float2*)(ea + (size_t)e*6 + 2);
        const float2 e45 = *(const float2*)(ea + (size_t)e*6 + 4);
        const float a0=e01.x, a1=e01.y, a2=e23.x, a3=e23.y, a4=e45.x, a5=e45.y;
#pragma unroll
        for (int j = 0; j < 16; ++j) {
            float c = b1[j];
            c += a0*w1[0*16+j]; c += a1*w1[1*16+j]; c += a2*w1[2*16+j];
            c += a3*w1[3*16+j]; c += a4*w1[4*16+j]; c += a5*w1[5*16+j];
            h[j] = fmaxf(c, 0.f);
        }
        h[16] = 1.f;
    }

    f32x16 acc0 = {}, acc1 = {};
#pragma unroll
    for (int s = 0; s < 17; ++s) {
        const float hs = h[s];
        float p0 = hs*xs[0], p1 = hs*xs[1], p2 = hs*xs[2], p3 = hs*xs[3];
        float p4 = hs*xs[4], p5 = hs*xs[5], p6 = hs*xs[6], p7 = hs*xs[7];
        uint4 uh = { pack2(p0,p1), pack2(p2,p3), pack2(p4,p5), pack2(p6,p7) };
        uint4 ul = { pack2(lof(p0),lof(p1)), pack2(lof(p2),lof(p3)),
                     pack2(lof(p4),lof(p5)), pack2(lof(p6),lof(p7)) };
        uint4 wh = s_tab[(s*2+0)*64 + lane];
        uint4 wl = s_tab[(s*2+1)*64 + lane];
        if (s & 1) {
            acc1 = __builtin_amdgcn_mfma_f32_32x32x16_bf16(asb(uh), asb(wh), acc1, 0, 0, 0);
            acc1 = __builtin_amdgcn_mfma_f32_32x32x16_bf16(asb(uh), asb(wl), acc1, 0, 0, 0);
            acc1 = __builtin_amdgcn_mfma_f32_32x32x16_bf16(asb(ul), asb(wh), acc1, 0, 0, 0);
        } else {
            acc0 = __builtin_amdgcn_mfma_f32_32x32x16_bf16(asb(uh), asb(wh), acc0, 0, 0, 0);
            acc0 = __builtin_amdgcn_mfma_f32_32x32x16_bf16(asb(uh), asb(wl), acc0, 0, 0, 0);
            acc0 = __builtin_amdgcn_mfma_f32_32x32x16_bf16(asb(ul), asb(wh), acc0, 0, 0, 0);
        }
    }

    float* mbase = msg + (size_t)tile*32*32;
    const int rb = g*4;
#pragma unroll
    for (int r = 0; r < 16; ++r) {
        int mr = (r&3) + 8*(r>>2) + rb;
        mbase[(size_t)mr*32 + m] = acc0[r] + acc1[r];
    }
}

__global__ __launch_bounds__(256) void k_conv2(
    const float* __restrict__ x, const float* __restrict__ ea,
    const int2* __restrict__ epair,
    const float* __restrict__ w1, const float* __restrict__ b1,
    const unsigned* __restrict__ bfrag, float* __restrict__ msg)
{
    __shared__ uint4 s_tab[17*2*64];
    __shared__ float lt[4][16*21];
    const int tid  = threadIdx.x;
    for (int i = tid; i < 17*2*64; i += 256) s_tab[i] = ((const uint4*)bfrag)[i];
    __syncthreads();
    const int lane = tid & 63;
    const int wid  = tid >> 6;
    const int m    = lane & 15;
    const int g    = lane >> 4;

    const int tile = blockIdx.x*4 + wid;
    const int p    = tile*16 + m;
    const int2 ep  = epair[p];
    const int e    = ep.x, src = ep.y;

    uint4 xh, xl;
    {
        const float4* xp = (const float4*)(x + (size_t)src*32 + g*8);
        float4 aa = xp[0], bb = xp[1];
        xh = (uint4){ pack2(aa.x,aa.y), pack2(aa.z,aa.w), pack2(bb.x,bb.y), pack2(bb.z,bb.w) };
        xl = (uint4){ pack2(lof(aa.x),lof(aa.y)), pack2(lof(aa.z),lof(aa.w)),
                      pack2(lof(bb.x),lof(bb.y)), pack2(lof(bb.z),lof(bb.w)) };
    }
    float h[17];
    {
        const float2 e01 = *(const float2*)(ea + (size_t)e*6);
        const float2 e23 = *(const float2*)(ea + (size_t)e*6 + 2);
        const float2 e45 = *(const float2*)(ea + (size_t)e*6 + 4);
        const float a0=e01.x, a1=e01.y, a2=e23.x, a3=e23.y, a4=e45.x, a5=e45.y;
#pragma unroll
        for (int j = 0; j < 16; ++j) {
            float c = b1[j];
            c += a0*w1[0*16+j]; c += a1*w1[1*16+j]; c += a2*w1[2*16+j];
            c += a3*w1[3*16+j]; c += a4*w1[4*16+j]; c += a5*w1[5*16+j];
            h[j] = fmaxf(c, 0.f);
        }
        h[16] = 1.f;
    }

    f32x4 macc = {};
#pragma unroll
    for (int s = 0; s < 17; ++s) {
        uint4 wh = s_tab[(s*2+0)*64 + lane];
        uint4 wl = s_tab[(s*2+1)*64 + lane];
        f32x4 t = {};
        t = __builtin_amdgcn_mfma_f32_16x16x32_bf16(asb(wh), asb(xh), t, 0, 0, 0);
        t = __builtin_amdgcn_mfma_f32_16x16x32_bf16(asb(wl), asb(xh), t, 0, 0, 0);
        t = __builtin_amdgcn_mfma_f32_16x16x32_bf16(asb(wh), asb(xl), t, 0, 0, 0);
        const float hs = h[s];
        macc.x += hs*t.x; macc.y += hs*t.y; macc.z += hs*t.z; macc.w += hs*t.w;
    }

    float* lw = lt[wid];
    lw[m*21 + g*4 + 0] = macc.x;
    lw[m*21 + g*4 + 1] = macc.y;
    lw[m*21 + g*4 + 2] = macc.z;
    lw[m*21 + g*4 + 3] = macc.w;
    wave_lds_fence();
    const int rrow = lane >> 2, fq = lane & 3;
    float o0 = lw[rrow*21 + fq*4 + 0];
    float o1 = lw[rrow*21 + fq*4 + 1];
    float o2 = lw[rrow*21 + fq*4 + 2];
    float o3 = lw[rrow*21 + fq*4 + 3];
    float4* mb = (float4*)(msg + (size_t)tile*256);
    mb[rrow*4 + fq] = make_float4(o0, o1, o2, o3);
}

__global__ __launch_bounds__(256) void k_reduce1(
    const float* __restrict__ msg, const int* __restrict__ offs,
    const float* __restrict__ x, const float* __restrict__ root,
    const float* __restrict__ bias, float* __restrict__ h1)
{
    __shared__ float s_r[512];
    __shared__ float s_b[32];
    int tid = threadIdx.x;
    for (int i = tid; i < 512; i += 256) s_r[i] = root[i];
    if (tid < 32) s_b[tid] = bias[tid];
    __syncthreads();
    int gid = blockIdx.x * 256 + tid;
    int n = gid >> 3, q = gid & 7;
    int s = offs[n], e = offs[n + 1];
    float4 acc = make_float4(s_b[4*q], s_b[4*q+1], s_b[4*q+2], s_b[4*q+3]);
    const float4* s_r4 = (const float4*)s_r;
    const float* xp = x + (size_t)n * 16;
#pragma unroll
    for (int i = 0; i < 16; ++i) {
        float xi = xp[i];
        float4 w = s_r4[i*8 + q];
        acc.x += xi*w.x; acc.y += xi*w.y; acc.z += xi*w.z; acc.w += xi*w.w;
    }
    for (int p = s; p < e; ++p) {
        float4 mr = ((const float4*)(msg + (size_t)p * 32))[q];
        acc.x += mr.x; acc.y += mr.y; acc.z += mr.z; acc.w += mr.w;
    }
    acc.x = fmaxf(acc.x, 0.f); acc.y = fmaxf(acc.y, 0.f);
    acc.z = fmaxf(acc.z, 0.f); acc.w = fmaxf(acc.w, 0.f);
    ((float4*)(h1 + (size_t)n * 32))[q] = acc;
}

__global__ __launch_bounds__(256) void k_reduce2(
    const float* __restrict__ msg, const int* __restrict__ offs,
    const float* __restrict__ h1, const float* __restrict__ root,
    const float* __restrict__ bias, float* __restrict__ h2)
{
    __shared__ float s_r[512];
    __shared__ float s_b[16];
    int tid = threadIdx.x;
    for (int i = tid; i < 512; i += 256) s_r[i] = root[i];
    if (tid < 16) s_b[tid] = bias[tid];
    __syncthreads();
    int gid = blockIdx.x * 256 + tid;
    int n = gid >> 2, q = gid & 3;
    int s = offs[n], e = offs[n + 1];
    float4 acc = make_float4(s_b[4*q], s_b[4*q+1], s_b[4*q+2], s_b[4*q+3]);
    const float4* s_r4 = (const float4*)s_r;
    const float* xp = h1 + (size_t)n * 32;
#pragma unroll
    for (int i = 0; i < 32; ++i) {
        float xi = xp[i];
        float4 w = s_r4[i*4 + q];
        acc.x += xi*w.x; acc.y += xi*w.y; acc.z += xi*w.z; acc.w += xi*w.w;
    }
    for (int p = s; p < e; ++p) {
        float4 mr = ((const float4*)(msg + (size_t)p * 16))[q];
        acc.x += mr.x; acc.y += mr.y; acc.z += mr.z; acc.w += mr.w;
    }
    acc.x = fmaxf(acc.x, 0.f); acc.y = fmaxf(acc.y, 0.f);
    acc.z = fmaxf(acc.z, 0.f); acc.w = fmaxf(acc.w, 0.f);
    ((float4*)(h2 + (size_t)n * 16))[q] = acc;
}

__global__ __launch_bounds__(64) void k_head(
    const float* __restrict__ h2, const float* __restrict__ x_att,
    const int* __restrict__ goffs,
    const float* __restrict__ l1w, const float* __restrict__ l1b,
    const float* __restrict__ l2w, const float* __restrict__ l2b,
    float* __restrict__ out)
{
    int g = blockIdx.x;
    int lane = threadIdx.x;
    int s = goffs[g], e = goffs[g + 1];
    __shared__ float v[32];
    __shared__ float hmid[8];
    int f = lane & 15, sub = lane >> 4;
    float acc = 0.f;
    for (int i = s + sub; i < e; i += 4) acc += h2[(size_t)i*16 + f];
    acc += __shfl_xor(acc, 16);
    acc += __shfl_xor(acc, 32);
    float cnt = fmaxf((float)(e - s), 1.0f);
    if (lane < 16) {
        v[lane]      = acc / cnt;
        v[16 + lane] = x_att[g*16 + lane];
    }
    __syncthreads();
    if (lane < 8) {
        float a = l1b[lane];
#pragma unroll
        for (int i = 0; i < 32; ++i) a += v[i] * l1w[i*8 + lane];
        hmid[lane] = a;
    }
    __syncthreads();
    if (lane == 0) {
        float a = l2b[0];
#pragma unroll
        for (int j = 0; j < 8; ++j) a += hmid[j] * l2w[j];
        out[g] = a;
    }
}

extern "C" void kernel_launch(void* const* d_in, const int* in_sizes, int n_in,
                              void* d_out, int out_size, void* d_ws, size_t ws_size,
                              hipStream_t stream) {
    Params P;
    P.x     = (const float*)d_in[0];
    P.ea    = (const float*)d_in[2];
    P.ei    = (const int*)d_in[4];
    P.batch = (const int*)d_in[5];
    P.w1a   = (const float*)d_in[6];
    P.b1a   = (const float*)d_in[7];
    P.w2a   = (const float*)d_in[8];
    P.b2a   = (const float*)d_in[9];
    P.roota = (const float*)d_in[10];
    P.biasa = (const float*)d_in[11];
    P.w1b   = (const float*)d_in[12];
    P.b1b   = (const float*)d_in[13];
    P.w2b   = (const float*)d_in[14];
    P.b2b   = (const float*)d_in[15];
    P.rootb = (const float*)d_in[16];
    P.biasb = (const float*)d_in[17];
    P.gw1   = (const float*)d_in[18];
    P.gb1   = (const float*)d_in[19];
    P.gw2   = (const float*)d_in[20];
    P.gb2   = (const float*)d_in[21];
    P.l1w   = (const float*)d_in[22];
    P.l1b   = (const float*)d_in[23];
    P.l2w   = (const float*)d_in[24];
    P.l2b   = (const float*)d_in[25];
    P.out   = (float*)d_out;

    float* h1    = (float*)d_ws;
    float* h2    = h1 + (size_t)NN * 32;
    float* x_att = h2 + (size_t)NN * 16;
    int*   goffs = (int*)(x_att + (size_t)NG * 16);
    int*   offs  = goffs + 2052;
    int*   cnt   = offs + 65540;
    int*   cur   = cnt + NN;
    int*   bsum  = cur + NN;
    int*   boff  = bsum + 256;
    int2*  epair = (int2*)(boff + 256);
    unsigned* f1 = (unsigned*)(epair + NE);
    unsigned* f2 = f1 + 8704;
    float* msg   = (float*)(f2 + 8704);

    P.h1 = h1; P.h2 = h2; P.x_att = x_att;
    P.goffs = goffs; P.offs = offs; P.cnt = cnt; P.cur = cur;
    P.bsum = bsum; P.boff = boff;
    P.epair = epair; P.f1 = f1; P.f2 = f2; P.msg = msg;

    // ---- cooperative path: size grid by queried occupancy ----
    int dev = 0;
    (void)hipGetDevice(&dev);
    int coopSupported = 0, nCU = 0, occ = 0;
    (void)hipDeviceGetAttribute(&coopSupported, hipDeviceAttributeCooperativeLaunch, dev);
    (void)hipDeviceGetAttribute(&nCU, hipDeviceAttributeMultiprocessorCount, dev);
    (void)hipOccupancyMaxActiveBlocksPerMultiprocessor(&occ, k_all, NTHR, 0);

    if (coopSupported && occ >= 1 && nCU >= 1) {
        long long grid = (long long)occ * nCU;
        if (grid > 512) grid = 512;
        void* args[] = { &P };
        hipError_t err = hipLaunchCooperativeKernel((const void*)k_all,
                              dim3((unsigned)grid), dim3(NTHR), args, 0, stream);
        if (err == hipSuccess) return;
    }

    // ---- fallback: R10 multi-kernel pipeline (known-good) ----
    k_setup<<<512, 256, 0, stream>>>(P.batch, P.w2a, P.b2a, P.w2b, P.b2b,
                                     cnt, cur, goffs, f1, f2);
    k_gateatt<<<NG, 64, 0, stream>>>(P.x, P.gw1, P.gb1, P.gw2, P.gb2, goffs, x_att);
    k_hist<<<NE/256, 256, 0, stream>>>(P.ei, cnt);
    k_scan_blk<<<NN/256, 256, 0, stream>>>(cnt, offs, bsum);
    k_scan_top<<<1, 256, 0, stream>>>(bsum, boff);
    k_scan_add<<<NN/256, 256, 0, stream>>>(offs, boff);
    k_scatter<<<NE/256, 256, 0, stream>>>(P.ei, offs, cur, epair);
    k_conv1<<<2048, 256, 0, stream>>>(P.x, P.ea, epair, P.w1a, P.b1a, f1, msg);
    k_reduce1<<<NN*8/256, 256, 0, stream>>>(msg, offs, P.x, P.roota, P.biasa, h1);
    k_conv2<<<4096, 256, 0, stream>>>(h1, P.ea, epair, P.w1b, P.b1b, f2, msg);
    k_reduce2<<<NN*4/256, 256, 0, stream>>>(msg, offs, h1, P.rootb, P.biasb, h2);
    k_head<<<NG, 64, 0, stream>>>(h2, x_att, goffs, P.l1w, P.l1b, P.l2w, P.l2b, P.out);
}

// Round 14
// 144.030 us; speedup vs baseline: 3.1582x; 3.1582x over previous
//
#include <hip/hip_runtime.h>

#define NN 65536
#define NE 262144
#define NG 2048

typedef __attribute__((ext_vector_type(16))) float f32x16;
typedef __attribute__((ext_vector_type(4)))  float f32x4;
typedef __attribute__((ext_vector_type(8)))  __bf16 bf16x8;

__device__ inline unsigned pack2(float a, float b) {
    return __builtin_amdgcn_perm(__float_as_uint(b), __float_as_uint(a), 0x07060302u);
}
__device__ inline float lof(float p) {
    return p - __uint_as_float(__float_as_uint(p) & 0xffff0000u);
}
__device__ inline bf16x8 asb(uint4 u) { return __builtin_bit_cast(bf16x8, u); }
__device__ inline void wave_lds_fence() {
    asm volatile("s_waitcnt lgkmcnt(0)" ::: "memory");
}

// ---------------- setup: zero cnt/cur + goffs + W-fragment prep --------------
__global__ __launch_bounds__(256) void k_setup(
    const int* __restrict__ batch,
    const float* __restrict__ w2a, const float* __restrict__ b2a,
    const float* __restrict__ w2b, const float* __restrict__ b2c,
    int* __restrict__ cnt, int* __restrict__ cur, int* __restrict__ goffs,
    unsigned* __restrict__ f1, unsigned* __restrict__ f2)
{
    int t = blockIdx.x * 256 + threadIdx.x;      // 0..131071
    if (t < NN) { cnt[t] = 0; cur[t] = 0; }
    if (t <= NG) {
        int lo = 0, hi = NN;
        while (lo < hi) {
            int mid = (lo + hi) >> 1;
            if (batch[mid] < t) lo = mid + 1; else hi = mid;
        }
        goffs[t] = lo;
    }
    if (t < 17408) {
        int c = t / 8704;
        int r = t - c * 8704;
        int d = r & 3;
        int l = (r >> 2) & 63;
        int tt = (r >> 8) & 1;
        int s = r >> 9;
        if (c == 0) {   // conv1 table: slot (l>>5)*8+j of K-step s, col o = l&31
            int n = l & 31, g = l >> 5;
            int j0 = 2*d;
            int c0 = (g*8 + j0)*32 + n;
            int c1 = c0 + 32;
            float a = (s < 16) ? w2a[s*512 + c0] : b2a[c0];
            float b = (s < 16) ? w2a[s*512 + c1] : b2a[c1];
            f1[r] = tt ? pack2(lof(a), lof(b)) : pack2(a, b);
        } else {        // conv2 table: slot (l>>4)*8+j of K-step s, row o = l&15
            int n = l & 15, g = l >> 4;
            int j0 = 2*d;
            int c0 = (g*8 + j0)*16 + n;
            int c1 = c0 + 16;
            float a = (s < 16) ? w2b[s*512 + c0] : b2c[c0];
            float b = (s < 16) ? w2b[s*512 + c1] : b2c[c1];
            f2[r] = tt ? pack2(lof(a), lof(b)) : pack2(a, b);
        }
    }
}

// ---------------- fused gate + attention pool (one block per graph) ----------
__global__ __launch_bounds__(64) void k_gateatt(const float* __restrict__ x,
    const float* __restrict__ gw1, const float* __restrict__ gb1,
    const float* __restrict__ gw2, const float* __restrict__ gb2,
    const int* __restrict__ goffs, float* __restrict__ x_att)
{
    __shared__ float sw[256];
    __shared__ float sb[16];
    __shared__ float sw2[16];
    __shared__ float sb2;
    __shared__ float gb[1024];
    const int g = blockIdx.x;
    const int lane = threadIdx.x;
    for (int i = lane; i < 256; i += 64) sw[i] = gw1[i];
    if (lane < 16) { sb[lane] = gb1[lane]; sw2[lane] = gw2[lane]; }
    if (lane == 0) sb2 = gb2[0];
    const int s = goffs[g], e = goffs[g + 1];
    const int cnt = e - s;
    if (cnt <= 0) {
        if (lane < 16) x_att[g*16 + lane] = 0.f;
        return;
    }
    const int cap = cnt < 1024 ? cnt : 1024;
    __syncthreads();
    for (int ii = lane; ii < cap; ii += 64) {
        const float4* xp = (const float4*)(x + (size_t)(s + ii) * 16);
        float xv[16];
#pragma unroll
        for (int i = 0; i < 4; ++i) {
            float4 tt = xp[i];
            xv[4*i] = tt.x; xv[4*i+1] = tt.y; xv[4*i+2] = tt.z; xv[4*i+3] = tt.w;
        }
        float gv = sb2;
#pragma unroll
        for (int j = 0; j < 16; ++j) {
            float a = sb[j];
#pragma unroll
            for (int i = 0; i < 16; ++i) a += xv[i] * sw[i*16 + j];
            gv += fmaxf(a, 0.f) * sw2[j];
        }
        gb[ii] = gv;
    }
    __syncthreads();
    float m = -1e30f;
    for (int ii = lane; ii < cap; ii += 64) m = fmaxf(m, gb[ii]);
#pragma unroll
    for (int d = 32; d; d >>= 1) m = fmaxf(m, __shfl_xor(m, d));
    float sum = 0.f;
    for (int ii = lane; ii < cap; ii += 64) {
        float ev = expf(gb[ii] - m);
        gb[ii] = ev;
        sum += ev;
    }
#pragma unroll
    for (int d = 32; d; d >>= 1) sum += __shfl_xor(sum, d);
    const float inv = 1.f / sum;
    __syncthreads();
    const int f = lane & 15, sub = lane >> 4;
    float acc = 0.f;
    for (int ii = sub; ii < cap; ii += 4)
        acc += gb[ii] * inv * x[(size_t)(s + ii)*16 + f];
    acc += __shfl_xor(acc, 16);
    acc += __shfl_xor(acc, 32);
    if (lane < 16) x_att[g*16 + f] = acc;
}

// ---------------- CSR build: histogram / scan / scatter ----------------------
__global__ __launch_bounds__(256) void k_hist(const int* __restrict__ ei, int* __restrict__ cnt)
{
    int e = blockIdx.x * 256 + threadIdx.x;
    if (e >= NE) return;
    atomicAdd(&cnt[ei[NE + e]], 1);
}

__global__ __launch_bounds__(256) void k_scan_blk(const int* __restrict__ cnt,
    int* __restrict__ offs, int* __restrict__ bsum)
{
    __shared__ int s[256];
    int t = threadIdx.x, b = blockIdx.x;
    int v = cnt[b*256 + t];
    s[t] = v;
    __syncthreads();
#pragma unroll
    for (int d = 1; d < 256; d <<= 1) {
        int add = (t >= d) ? s[t - d] : 0;
        __syncthreads();
        s[t] += add;
        __syncthreads();
    }
    offs[b*256 + t] = s[t] - v;
    if (t == 255) bsum[b] = s[255];
}

__global__ __launch_bounds__(256) void k_scan_top(const int* __restrict__ bsum,
    int* __restrict__ boff)
{
    __shared__ int s[256];
    int t = threadIdx.x;
    int v = bsum[t];
    s[t] = v;
    __syncthreads();
#pragma unroll
    for (int d = 1; d < 256; d <<= 1) {
        int add = (t >= d) ? s[t - d] : 0;
        __syncthreads();
        s[t] += add;
        __syncthreads();
    }
    boff[t] = s[t] - v;
}

__global__ __launch_bounds__(256) void k_scan_add(int* __restrict__ offs,
    const int* __restrict__ boff)
{
    int i = blockIdx.x * 256 + threadIdx.x;
    if (i == 0) offs[NN] = NE;
    if (i >= NN) return;
    offs[i] += boff[i >> 8];
}

__global__ __launch_bounds__(256) void k_scatter(const int* __restrict__ ei,
    const int* __restrict__ offs, int* __restrict__ cur, int2* __restrict__ epair)
{
    int e = blockIdx.x * 256 + threadIdx.x;
    if (e >= NE) return;
    int d = ei[NE + e];
    int pos = offs[d] + atomicAdd(&cur[d], 1);
    epair[pos] = make_int2(e, ei[e]);
}

// ---------------- conv1: NNConv(16->32) via MFMA 32x32x16, ILP-2 -------------
// Two independent tiles per wave: two gather chains + two MFMA chains overlap;
// W-table LDS reads shared by both tiles. Table staged in LDS per block.
__global__ __launch_bounds__(256) void k_conv1(
    const float* __restrict__ x, const float* __restrict__ ea,
    const int2* __restrict__ epair,
    const float* __restrict__ w1, const float* __restrict__ b1,
    const unsigned* __restrict__ bfrag, float* __restrict__ msg)
{
    __shared__ uint4 s_tab[17*2*64];
    const int tid  = threadIdx.x;
    for (int i = tid; i < 17*2*64; i += 256) s_tab[i] = ((const uint4*)bfrag)[i];
    __syncthreads();
    const int lane = tid & 63;
    const int wid  = tid >> 6;
    const int m    = lane & 31;     // edge in tile; for D: col = out channel
    const int g    = lane >> 5;     // k-group

    const int tA = blockIdx.x*8 + wid*2;
    const int tB = tA + 1;
    const int2 epA = epair[tA*32 + m];
    const int2 epB = epair[tB*32 + m];

    float xsA[8], xsB[8];
    {
        const float4* xpA = (const float4*)(x + (size_t)epA.y*16 + g*8);
        const float4* xpB = (const float4*)(x + (size_t)epB.y*16 + g*8);
        float4 a0 = xpA[0], a1 = xpA[1], b0 = xpB[0], b1v = xpB[1];
        xsA[0]=a0.x; xsA[1]=a0.y; xsA[2]=a0.z; xsA[3]=a0.w;
        xsA[4]=a1.x; xsA[5]=a1.y; xsA[6]=a1.z; xsA[7]=a1.w;
        xsB[0]=b0.x; xsB[1]=b0.y; xsB[2]=b0.z; xsB[3]=b0.w;
        xsB[4]=b1v.x; xsB[5]=b1v.y; xsB[6]=b1v.z; xsB[7]=b1v.w;
    }
    float hA[17], hB[17];
    {
        const float2 a01 = *(const float2*)(ea + (size_t)epA.x*6);
        const float2 a23 = *(const float2*)(ea + (size_t)epA.x*6 + 2);
        const float2 a45 = *(const float2*)(ea + (size_t)epA.x*6 + 4);
        const float2 b01 = *(const float2*)(ea + (size_t)epB.x*6);
        const float2 b23 = *(const float2*)(ea + (size_t)epB.x*6 + 2);
        const float2 b45 = *(const float2*)(ea + (size_t)epB.x*6 + 4);
#pragma unroll
        for (int j = 0; j < 16; ++j) {
            float w0 = w1[0*16+j], w1v = w1[1*16+j], w2v = w1[2*16+j];
            float w3 = w1[3*16+j], w4 = w1[4*16+j], w5 = w1[5*16+j];
            float bb = b1[j];
            float cA = bb + a01.x*w0 + a01.y*w1v + a23.x*w2v + a23.y*w3 + a45.x*w4 + a45.y*w5;
            float cB = bb + b01.x*w0 + b01.y*w1v + b23.x*w2v + b23.y*w3 + b45.x*w4 + b45.y*w5;
            hA[j] = fmaxf(cA, 0.f);
            hB[j] = fmaxf(cB, 0.f);
        }
        hA[16] = 1.f; hB[16] = 1.f;
    }

    f32x16 accA = {}, accB = {};
#pragma unroll
    for (int s = 0; s < 17; ++s) {
        const float ha = hA[s], hb = hB[s];
        float pA0 = ha*xsA[0], pA1 = ha*xsA[1], pA2 = ha*xsA[2], pA3 = ha*xsA[3];
        float pA4 = ha*xsA[4], pA5 = ha*xsA[5], pA6 = ha*xsA[6], pA7 = ha*xsA[7];
        float pB0 = hb*xsB[0], pB1 = hb*xsB[1], pB2 = hb*xsB[2], pB3 = hb*xsB[3];
        float pB4 = hb*xsB[4], pB5 = hb*xsB[5], pB6 = hb*xsB[6], pB7 = hb*xsB[7];
        uint4 uhA = { pack2(pA0,pA1), pack2(pA2,pA3), pack2(pA4,pA5), pack2(pA6,pA7) };
        uint4 ulA = { pack2(lof(pA0),lof(pA1)), pack2(lof(pA2),lof(pA3)),
                      pack2(lof(pA4),lof(pA5)), pack2(lof(pA6),lof(pA7)) };
        uint4 uhB = { pack2(pB0,pB1), pack2(pB2,pB3), pack2(pB4,pB5), pack2(pB6,pB7) };
        uint4 ulB = { pack2(lof(pB0),lof(pB1)), pack2(lof(pB2),lof(pB3)),
                      pack2(lof(pB4),lof(pB5)), pack2(lof(pB6),lof(pB7)) };
        uint4 wh = s_tab[(s*2+0)*64 + lane];
        uint4 wl = s_tab[(s*2+1)*64 + lane];
        accA = __builtin_amdgcn_mfma_f32_32x32x16_bf16(asb(uhA), asb(wh), accA, 0, 0, 0);
        accB = __builtin_amdgcn_mfma_f32_32x32x16_bf16(asb(uhB), asb(wh), accB, 0, 0, 0);
        accA = __builtin_amdgcn_mfma_f32_32x32x16_bf16(asb(uhA), asb(wl), accA, 0, 0, 0);
        accB = __builtin_amdgcn_mfma_f32_32x32x16_bf16(asb(uhB), asb(wl), accB, 0, 0, 0);
        accA = __builtin_amdgcn_mfma_f32_32x32x16_bf16(asb(ulA), asb(wh), accA, 0, 0, 0);
        accB = __builtin_amdgcn_mfma_f32_32x32x16_bf16(asb(ulB), asb(wh), accB, 0, 0, 0);
    }

    float* mbA = msg + (size_t)tA*32*32;
    float* mbB = msg + (size_t)tB*32*32;
    const int rb = g*4;
#pragma unroll
    for (int r = 0; r < 16; ++r) {
        int mr = (r&3) + 8*(r>>2) + rb;          // D row = edge-in-tile
        mbA[(size_t)mr*32 + m] = accA[r];        // D col (lane&31) = out channel
        mbB[(size_t)mr*32 + m] = accB[r];
    }
}

// ---------------- conv2: NNConv(32->16), h-hoisted MFMA 16x16x32, ILP-2 ------
__global__ __launch_bounds__(256) void k_conv2(
    const float* __restrict__ x, const float* __restrict__ ea,
    const int2* __restrict__ epair,
    const float* __restrict__ w1, const float* __restrict__ b1,
    const unsigned* __restrict__ bfrag, float* __restrict__ msg)
{
    __shared__ uint4 s_tab[17*2*64];
    __shared__ float lt[4][16*21];
    const int tid  = threadIdx.x;
    for (int i = tid; i < 17*2*64; i += 256) s_tab[i] = ((const uint4*)bfrag)[i];
    __syncthreads();
    const int lane = tid & 63;
    const int wid  = tid >> 6;
    const int m    = lane & 15;     // B col = edge in tile
    const int g    = lane >> 4;     // 8-slot group (i-range g*8..g*8+7)

    const int tA = blockIdx.x*8 + wid*2;
    const int tB = tA + 1;
    const int2 epA = epair[tA*16 + m];
    const int2 epB = epair[tB*16 + m];

    uint4 xhA, xlA, xhB, xlB;
    {
        const float4* xpA = (const float4*)(x + (size_t)epA.y*32 + g*8);
        const float4* xpB = (const float4*)(x + (size_t)epB.y*32 + g*8);
        float4 a0 = xpA[0], a1 = xpA[1], b0 = xpB[0], b1v = xpB[1];
        xhA = (uint4){ pack2(a0.x,a0.y), pack2(a0.z,a0.w), pack2(a1.x,a1.y), pack2(a1.z,a1.w) };
        xlA = (uint4){ pack2(lof(a0.x),lof(a0.y)), pack2(lof(a0.z),lof(a0.w)),
                       pack2(lof(a1.x),lof(a1.y)), pack2(lof(a1.z),lof(a1.w)) };
        xhB = (uint4){ pack2(b0.x,b0.y), pack2(b0.z,b0.w), pack2(b1v.x,b1v.y), pack2(b1v.z,b1v.w) };
        xlB = (uint4){ pack2(lof(b0.x),lof(b0.y)), pack2(lof(b0.z),lof(b0.w)),
                       pack2(lof(b1v.x),lof(b1v.y)), pack2(lof(b1v.z),lof(b1v.w)) };
    }
    float hA[17], hB[17];
    {
        const float2 a01 = *(const float2*)(ea + (size_t)epA.x*6);
        const float2 a23 = *(const float2*)(ea + (size_t)epA.x*6 + 2);
        const float2 a45 = *(const float2*)(ea + (size_t)epA.x*6 + 4);
        const float2 b01 = *(const float2*)(ea + (size_t)epB.x*6);
        const float2 b23 = *(const float2*)(ea + (size_t)epB.x*6 + 2);
        const float2 b45 = *(const float2*)(ea + (size_t)epB.x*6 + 4);
#pragma unroll
        for (int j = 0; j < 16; ++j) {
            float w0 = w1[0*16+j], w1v = w1[1*16+j], w2v = w1[2*16+j];
            float w3 = w1[3*16+j], w4 = w1[4*16+j], w5 = w1[5*16+j];
            float bb = b1[j];
            float cA = bb + a01.x*w0 + a01.y*w1v + a23.x*w2v + a23.y*w3 + a45.x*w4 + a45.y*w5;
            float cB = bb + b01.x*w0 + b01.y*w1v + b23.x*w2v + b23.y*w3 + b45.x*w4 + b45.y*w5;
            hA[j] = fmaxf(cA, 0.f);
            hB[j] = fmaxf(cB, 0.f);
        }
        hA[16] = 1.f; hB[16] = 1.f;
    }

    f32x4 mA = {}, mB = {};
#pragma unroll
    for (int s = 0; s < 17; ++s) {
        uint4 wh = s_tab[(s*2+0)*64 + lane];
        uint4 wl = s_tab[(s*2+1)*64 + lane];
        f32x4 tA4 = {}, tB4 = {};
        tA4 = __builtin_amdgcn_mfma_f32_16x16x32_bf16(asb(wh), asb(xhA), tA4, 0, 0, 0);
        tB4 = __builtin_amdgcn_mfma_f32_16x16x32_bf16(asb(wh), asb(xhB), tB4, 0, 0, 0);
        tA4 = __builtin_amdgcn_mfma_f32_16x16x32_bf16(asb(wl), asb(xhA), tA4, 0, 0, 0);
        tB4 = __builtin_amdgcn_mfma_f32_16x16x32_bf16(asb(wl), asb(xhB), tB4, 0, 0, 0);
        tA4 = __builtin_amdgcn_mfma_f32_16x16x32_bf16(asb(wh), asb(xlA), tA4, 0, 0, 0);
        tB4 = __builtin_amdgcn_mfma_f32_16x16x32_bf16(asb(wh), asb(xlB), tB4, 0, 0, 0);
        const float ha = hA[s], hb = hB[s];
        mA.x += ha*tA4.x; mA.y += ha*tA4.y; mA.z += ha*tA4.z; mA.w += ha*tA4.w;
        mB.x += hb*tB4.x; mB.y += hb*tB4.y; mB.z += hb*tB4.z; mB.w += hb*tB4.w;
    }

    // D: row o = g*4+r, col edge = m. Transpose via LDS [edge][o] pad 21, twice.
    float* lw = lt[wid];
    const int rrow = lane >> 2, fq = lane & 3;
    lw[m*21 + g*4 + 0] = mA.x;
    lw[m*21 + g*4 + 1] = mA.y;
    lw[m*21 + g*4 + 2] = mA.z;
    lw[m*21 + g*4 + 3] = mA.w;
    wave_lds_fence();
    float a0 = lw[rrow*21 + fq*4 + 0];
    float a1 = lw[rrow*21 + fq*4 + 1];
    float a2 = lw[rrow*21 + fq*4 + 2];
    float a3 = lw[rrow*21 + fq*4 + 3];
    wave_lds_fence();                       // reads done before overwrite
    ((float4*)(msg + (size_t)tA*256))[rrow*4 + fq] = make_float4(a0, a1, a2, a3);

    lw[m*21 + g*4 + 0] = mB.x;
    lw[m*21 + g*4 + 1] = mB.y;
    lw[m*21 + g*4 + 2] = mB.z;
    lw[m*21 + g*4 + 3] = mB.w;
    wave_lds_fence();
    float b0 = lw[rrow*21 + fq*4 + 0];
    float b1v = lw[rrow*21 + fq*4 + 1];
    float b2 = lw[rrow*21 + fq*4 + 2];
    float b3 = lw[rrow*21 + fq*4 + 3];
    ((float4*)(msg + (size_t)tB*256))[rrow*4 + fq] = make_float4(b0, b1v, b2, b3);
}

// ---------------- reduce1: h1 = relu(segsum(msg) + x@root1 + bias1) ----------
__global__ __launch_bounds__(256) void k_reduce1(
    const float* __restrict__ msg, const int* __restrict__ offs,
    const float* __restrict__ x, const float* __restrict__ root,
    const float* __restrict__ bias, float* __restrict__ h1)
{
    __shared__ float s_r[512];   // [16][32]
    __shared__ float s_b[32];
    int tid = threadIdx.x;
    for (int i = tid; i < 512; i += 256) s_r[i] = root[i];
    if (tid < 32) s_b[tid] = bias[tid];
    __syncthreads();
    int gid = blockIdx.x * 256 + tid;
    int n = gid >> 3, q = gid & 7;
    int s = offs[n], e = offs[n + 1];
    float4 acc = make_float4(s_b[4*q], s_b[4*q+1], s_b[4*q+2], s_b[4*q+3]);
    const float4* s_r4 = (const float4*)s_r;
    const float4* xp4 = (const float4*)(x + (size_t)n * 16);
#pragma unroll
    for (int ii = 0; ii < 4; ++ii) {
        float4 xv = xp4[ii];
        float4 w0 = s_r4[(ii*4+0)*8 + q];
        float4 w1 = s_r4[(ii*4+1)*8 + q];
        float4 w2 = s_r4[(ii*4+2)*8 + q];
        float4 w3 = s_r4[(ii*4+3)*8 + q];
        acc.x += xv.x*w0.x + xv.y*w1.x + xv.z*w2.x + xv.w*w3.x;
        acc.y += xv.x*w0.y + xv.y*w1.y + xv.z*w2.y + xv.w*w3.y;
        acc.z += xv.x*w0.z + xv.y*w1.z + xv.z*w2.z + xv.w*w3.z;
        acc.w += xv.x*w0.w + xv.y*w1.w + xv.z*w2.w + xv.w*w3.w;
    }
    for (int p = s; p < e; ++p) {
        float4 mr = ((const float4*)(msg + (size_t)p * 32))[q];
        acc.x += mr.x; acc.y += mr.y; acc.z += mr.z; acc.w += mr.w;
    }
    acc.x = fmaxf(acc.x, 0.f); acc.y = fmaxf(acc.y, 0.f);
    acc.z = fmaxf(acc.z, 0.f); acc.w = fmaxf(acc.w, 0.f);
    ((float4*)(h1 + (size_t)n * 32))[q] = acc;
}

// ---------------- reduce2: h2 = relu(segsum(msg) + h1@root2 + bias2) ---------
__global__ __launch_bounds__(256) void k_reduce2(
    const float* __restrict__ msg, const int* __restrict__ offs,
    const float* __restrict__ h1, const float* __restrict__ root,
    const float* __restrict__ bias, float* __restrict__ h2)
{
    __shared__ float s_r[512];   // [32][16]
    __shared__ float s_b[16];
    int tid = threadIdx.x;
    for (int i = tid; i < 512; i += 256) s_r[i] = root[i];
    if (tid < 16) s_b[tid] = bias[tid];
    __syncthreads();
    int gid = blockIdx.x * 256 + tid;
    int n = gid >> 2, q = gid & 3;
    int s = offs[n], e = offs[n + 1];
    float4 acc = make_float4(s_b[4*q], s_b[4*q+1], s_b[4*q+2], s_b[4*q+3]);
    const float4* s_r4 = (const float4*)s_r;
    const float4* xp4 = (const float4*)(h1 + (size_t)n * 32);
#pragma unroll
    for (int ii = 0; ii < 8; ++ii) {
        float4 xv = xp4[ii];
        float4 w0 = s_r4[(ii*4+0)*4 + q];
        float4 w1 = s_r4[(ii*4+1)*4 + q];
        float4 w2 = s_r4[(ii*4+2)*4 + q];
        float4 w3 = s_r4[(ii*4+3)*4 + q];
        acc.x += xv.x*w0.x + xv.y*w1.x + xv.z*w2.x + xv.w*w3.x;
        acc.y += xv.x*w0.y + xv.y*w1.y + xv.z*w2.y + xv.w*w3.y;
        acc.z += xv.x*w0.z + xv.y*w1.z + xv.z*w2.z + xv.w*w3.z;
        acc.w += xv.x*w0.w + xv.y*w1.w + xv.z*w2.w + xv.w*w3.w;
    }
    for (int p = s; p < e; ++p) {
        float4 mr = ((const float4*)(msg + (size_t)p * 16))[q];
        acc.x += mr.x; acc.y += mr.y; acc.z += mr.z; acc.w += mr.w;
    }
    acc.x = fmaxf(acc.x, 0.f); acc.y = fmaxf(acc.y, 0.f);
    acc.z = fmaxf(acc.z, 0.f); acc.w = fmaxf(acc.w, 0.f);
    ((float4*)(h2 + (size_t)n * 16))[q] = acc;
}

// ---------------- mean pool + concat + head ----------------------------------
__global__ __launch_bounds__(64) void k_head(
    const float* __restrict__ h2, const float* __restrict__ x_att,
    const int* __restrict__ goffs,
    const float* __restrict__ l1w, const float* __restrict__ l1b,
    const float* __restrict__ l2w, const float* __restrict__ l2b,
    float* __restrict__ out)
{
    int g = blockIdx.x;
    int lane = threadIdx.x;
    int s = goffs[g], e = goffs[g + 1];
    __shared__ float v[32];
    __shared__ float hmid[8];
    int f = lane & 15, sub = lane >> 4;
    float acc = 0.f;
    for (int i = s + sub; i < e; i += 4) acc += h2[(size_t)i*16 + f];
    acc += __shfl_xor(acc, 16);
    acc += __shfl_xor(acc, 32);
    float cnt = fmaxf((float)(e - s), 1.0f);
    if (lane < 16) {
        v[lane]      = acc / cnt;
        v[16 + lane] = x_att[g*16 + lane];
    }
    __syncthreads();
    if (lane < 8) {
        float a = l1b[lane];
#pragma unroll
        for (int i = 0; i < 32; ++i) a += v[i] * l1w[i*8 + lane];
        hmid[lane] = a;
    }
    __syncthreads();
    if (lane == 0) {
        float a = l2b[0];
#pragma unroll
        for (int j = 0; j < 8; ++j) a += hmid[j] * l2w[j];
        out[g] = a;
    }
}

extern "C" void kernel_launch(void* const* d_in, const int* in_sizes, int n_in,
                              void* d_out, int out_size, void* d_ws, size_t ws_size,
                              hipStream_t stream) {
    const float* x_p    = (const float*)d_in[0];
    const float* ea_p   = (const float*)d_in[2];
    const int*   ei     = (const int*)d_in[4];
    const int*   batch  = (const int*)d_in[5];
    const float* nn1_w1 = (const float*)d_in[6];
    const float* nn1_b1 = (const float*)d_in[7];
    const float* nn1_w2 = (const float*)d_in[8];
    const float* nn1_b2 = (const float*)d_in[9];
    const float* root1  = (const float*)d_in[10];
    const float* bias1  = (const float*)d_in[11];
    const float* nn2_w1 = (const float*)d_in[12];
    const float* nn2_b1 = (const float*)d_in[13];
    const float* nn2_w2 = (const float*)d_in[14];
    const float* nn2_b2 = (const float*)d_in[15];
    const float* root2  = (const float*)d_in[16];
    const float* bias2  = (const float*)d_in[17];
    const float* gw1    = (const float*)d_in[18];
    const float* gb1    = (const float*)d_in[19];
    const float* gw2    = (const float*)d_in[20];
    const float* gb2    = (const float*)d_in[21];
    const float* l1w    = (const float*)d_in[22];
    const float* l1b    = (const float*)d_in[23];
    const float* l2w    = (const float*)d_in[24];
    const float* l2b    = (const float*)d_in[25];

    // -------- workspace layout --------
    float*    h1     = (float*)d_ws;                     // NN*32
    float*    h2     = h1 + (size_t)NN * 32;             // NN*16
    float*    x_att  = h2 + (size_t)NN * 16;             // NG*16
    int*      goffs  = (int*)(x_att + (size_t)NG * 16);  // 2052
    int*      offs   = goffs + 2052;                     // 65540
    int*      cnt    = offs + 65540;                     // NN
    int*      cur    = cnt + NN;                         // NN
    int*      bsum   = cur + NN;                         // 256
    int*      boff   = bsum + 256;                       // 256
    int2*     epair  = (int2*)(boff + 256);              // NE int2 (8B-aligned)
    unsigned* bfrag1 = (unsigned*)(epair + NE);          // 8704
    unsigned* bfrag2 = bfrag1 + 8704;                    // 8704
    float*    msg    = (float*)(bfrag2 + 8704);          // NE*32 (conv1) / NE*16 (conv2)

    // -------- setup (zero cnt/cur, goffs, W fragments) --------
    k_setup<<<512, 256, 0, stream>>>(batch, nn1_w2, nn1_b2, nn2_w2, nn2_b2,
                                     cnt, cur, goffs, bfrag1, bfrag2);

    // -------- fused gate + attention pool --------
    k_gateatt<<<NG, 64, 0, stream>>>(x_p, gw1, gb1, gw2, gb2, goffs, x_att);

    // -------- CSR build over dst --------
    k_hist<<<NE/256, 256, 0, stream>>>(ei, cnt);
    k_scan_blk<<<NN/256, 256, 0, stream>>>(cnt, offs, bsum);
    k_scan_top<<<1, 256, 0, stream>>>(bsum, boff);
    k_scan_add<<<NN/256, 256, 0, stream>>>(offs, boff);
    k_scatter<<<NE/256, 256, 0, stream>>>(ei, offs, cur, epair);

    // -------- conv1 + fused node update --------
    k_conv1<<<1024, 256, 0, stream>>>(x_p, ea_p, epair, nn1_w1, nn1_b1, bfrag1, msg);
    k_reduce1<<<NN*8/256, 256, 0, stream>>>(msg, offs, x_p, root1, bias1, h1);

    // -------- conv2 + fused node update --------
    k_conv2<<<2048, 256, 0, stream>>>(h1, ea_p, epair, nn2_w1, nn2_b1, bfrag2, msg);
    k_reduce2<<<NN*4/256, 256, 0, stream>>>(msg, offs, h1, root2, bias2, h2);

    // -------- head --------
    k_head<<<NG, 64, 0, stream>>>(h2, x_att, goffs, l1w, l1b, l2w, l2b, (float*)d_out);
}